// Round 10
// baseline (365.841 us; speedup 1.0000x reference)
//
#include <hip/hip_runtime.h>
#include <hip/hip_bf16.h>

// Round 10: persistent mega-kernel (512 blocks, 2/CU co-resident, software grid
// barrier) running all 5 validated stages; plus one 4-byte memset for the
// barrier counter. Stage bodies are the round-9 validated code with
// blockIdx->job plumbing; y-GEMM re-tiled 64x64 (512 jobs, 2 blocks/CU).
//   stage0 prep   : convert | h2b | tpWdec | tpWout' | tpWmlp | Xcat0 | occup | stats0
//   stage1 gemm2  : z0 hd = h@Wdec+benc+bdec -> bf16 d_out ; z1 P1 = Xcat0@Wout'+bout -> f32
//   stage2 ectx   : softmax ctx; pool = bf16(P1 + ctx*w0) -> d_out
//   stage3 ygemm  : y = pool@Wmlp + bmlp (64x64 tiles) + fused col stats
//   stage4 norm   : batchnorm(axis0) + relu -> d_out
//
// ws (floats): conv 0..279552 (end0 rel4096 scn8192 Wenc270336 benc271360
//   bdec272384 wful273408 bout274432 bmlp275456 gam276480 bet277504 w0 278528)
//   occ@280576(131072) stats@411648(2048) P1@413696(2097152)
// bf16 u0=(ushort*)(ws+2510848): hbf0 WdecT131072 WoutT196608 WmlpT294912
//   Xcat0 1343488 y_mf 1540096..3637248 ; barrier cnt @ byte 17317888.

#define NG2  64
#define NPTS 4096
#define NBLK 512

typedef unsigned short ushort_t;
typedef __attribute__((ext_vector_type(8))) short bf16x8;
typedef __attribute__((ext_vector_type(4))) float f32x4;

struct PrepPtrs { const void* p[16]; };

__device__ __forceinline__ float bf2f(ushort_t u) {
  return __uint_as_float(((unsigned int)u) << 16);
}
__device__ __forceinline__ ushort_t f2bf(float f) {
  __hip_bfloat16 b = __float2bfloat16(f);
  return *reinterpret_cast<ushort_t*>(&b);
}
__device__ __forceinline__ float lde(const void* p, size_t i, int fl) {
  return fl ? bf2f(((const ushort_t*)p)[i]) : ((const float*)p)[i];
}

// grid barrier: monotone counter, phase target = NBLK*phase
__device__ __forceinline__ void gbar(unsigned* cnt, unsigned want) {
  __syncthreads();
  if (threadIdx.x == 0) {
    __threadfence();                       // release (device scope)
    atomicAdd(cnt, 1u);
    while (atomicAdd(cnt, 0u) < want) __builtin_amdgcn_s_sleep(2);
    __threadfence();                       // acquire
  }
  __syncthreads();
}

// ---------------------------------------------------------------- stage bodies
__device__ __forceinline__ void tp_body(const void* in, int fl, int job,
                                        int Kin, int Kpad, ushort_t* out) {
  __shared__ ushort_t t[32][40];
  int n0 = (job & 31) * 32, k0 = (job >> 5) * 32;
  int r = threadIdx.x >> 3, c4 = (threadIdx.x & 7) * 4;
  ushort4 v = make_ushort4(0, 0, 0, 0);
  if (k0 + r < Kin) {
    size_t off = (size_t)(k0 + r) * 1024 + n0 + c4;
    if (fl) {
      v = *(const ushort4*)((const ushort_t*)in + off);
    } else {
      float4 f = *(const float4*)((const float*)in + off);
      v = make_ushort4(f2bf(f.x), f2bf(f.y), f2bf(f.z), f2bf(f.w));
    }
  }
  *(ushort4*)(&t[r][c4]) = v;
  __syncthreads();
  int n = threadIdx.x >> 3, kk = (threadIdx.x & 7) * 4;
  ushort4 o = make_ushort4(t[kk][n], t[kk + 1][n], t[kk + 2][n], t[kk + 3][n]);
  *(ushort4*)(out + (size_t)(n0 + n) * Kpad + k0 + kk) = o;
}

// jobs: [0,273)convert [273,401)h2b [401,465)tpWdec [465,561)tpWout'
//       [561,1585)tpWmlp [1585,1777)Xcat0 [1777,3825)occupancy [3825]stats0
__device__ void prep_job(const PrepPtrs& ptrs, int fl, int b,
                         float* conv, ushort_t* hbf, ushort_t* WdecT,
                         ushort_t* WoutT, ushort_t* WmlpT, ushort_t* Xcat0,
                         float* occ, float* stats) {
  if (b < 273) {
    const int ends[12] = {4096, 8192, 270336, 271360, 272384, 273408,
                          274432, 275456, 276480, 277504, 278528, 279552};
    int idx = (b * 256 + threadIdx.x) * 4;
    int seg = 0, base = 0;
#pragma unroll
    for (int s = 0; s < 11; s++) {
      if (idx >= ends[s]) { seg = s + 1; base = ends[s]; }
    }
    int off = idx - base;
    float4 o;
    if (fl) {
      const unsigned int* src = (const unsigned int*)ptrs.p[4 + seg];
      uint2 u = *(const uint2*)(src + (off >> 1));
      o.x = __uint_as_float((u.x & 0xFFFFu) << 16);
      o.y = __uint_as_float(u.x & 0xFFFF0000u);
      o.z = __uint_as_float((u.y & 0xFFFFu) << 16);
      o.w = __uint_as_float(u.y & 0xFFFF0000u);
    } else {
      o = *(const float4*)((const float*)ptrs.p[4 + seg] + off);
    }
    *(float4*)(conv + idx) = o;
  } else if (b < 401) {
    int i = (b - 273) * 256 + threadIdx.x;
    if (fl) {
      ((ushort4*)hbf)[i] = ((const ushort4*)ptrs.p[0])[i];
    } else {
      float4 f = ((const float4*)ptrs.p[0])[i];
      ((ushort4*)hbf)[i] = make_ushort4(f2bf(f.x), f2bf(f.y), f2bf(f.z), f2bf(f.w));
    }
  } else if (b < 465) {
    tp_body(ptrs.p[1], fl, b - 401, 64, 64, WdecT);
  } else if (b < 561) {
    const void* wout1 = fl ? (const void*)((const ushort_t*)ptrs.p[2] + 1024)
                           : (const void*)((const float*)ptrs.p[2] + 1024);
    tp_body(wout1, fl, b - 465, 68, 96, WoutT);
  } else if (b < 1585) {
    tp_body(ptrs.p[3], fl, b - 561, 1024, 1024, WmlpT);
  } else if (b < 1777) {
    int flat = (b - 1585) * 256 + threadIdx.x;
    int e4 = flat * 4;
    int r = e4 / 96, c = e4 - r * 96;
    ushort4 v = make_ushort4(0, 0, 0, 0);
    if (c < 64) {
      if (fl) v = *(const ushort4*)((const ushort_t*)ptrs.p[0] + r * 64 + c);
      else {
        float4 f = *(const float4*)((const float*)ptrs.p[0] + r * 64 + c);
        v = make_ushort4(f2bf(f.x), f2bf(f.y), f2bf(f.z), f2bf(f.w));
      }
    } else if (c == 64) {
      v.x = f2bf(lde(ptrs.p[4], 2 * r, fl));
      v.y = f2bf(lde(ptrs.p[4], 2 * r + 1, fl));
      v.z = f2bf(lde(ptrs.p[5], 2 * r, fl));
      v.w = f2bf(lde(ptrs.p[5], 2 * r + 1, fl));
    }
    *(ushort4*)(Xcat0 + e4) = v;
  } else if (b < 3825) {
    int i = b - 1777;
    int s = i >> 6;
    __shared__ float cnth[NG2];
    if (threadIdx.x < NG2) cnth[threadIdx.x] = 0.0f;
    __syncthreads();
    float ex = lde(ptrs.p[4], 2 * i, fl), ey = lde(ptrs.p[4], 2 * i + 1, fl);
    float tlx = ex - 1.0f, tly = ey + 1.0f, brx = ex + 1.0f, bry = ey - 1.0f;
    const void* scn = ptrs.p[6];
    for (int p = threadIdx.x; p < NPTS; p += 256) {
      size_t o2 = (size_t)s * NPTS * 2 + 2 * p;
      float sx = lde(scn, o2, fl), sy = lde(scn, o2 + 1, fl);
      bool oob = (sx >= brx) || (sx <= tlx) || (sy >= tly) || (sy <= bry);
      if (!oob) {
        int cx = (int)floorf((sx - tlx) * 0.5f * 8.0f);
        int cy = (int)floorf((tly - sy) * 0.5f * 8.0f);
        int cell = cx + cy * 8;
        if (cell >= 0 && cell < NG2) atomicAdd(&cnth[cell], 1.0f);
      }
    }
    __syncthreads();
    if (threadIdx.x < NG2) occ[i * NG2 + threadIdx.x] = cnth[threadIdx.x];
  } else {
#pragma unroll
    for (int k = 0; k < 8; k++) stats[threadIdx.x + 256 * k] = 0.0f;
  }
}

// validated 64x128 MFMA body, job-indexed. EPI0: bf16(acc+b1+b2); EPI3: f32 acc+b1
template <int K, int EPI>
__device__ void mgemm_body(ushort_t* As, ushort_t* Bs, int m0, int n0,
                           const ushort_t* __restrict__ A, int lda,
                           const ushort_t* __restrict__ BT, int ldb,
                           const float* __restrict__ bias1, const float* __restrict__ bias2,
                           ushort_t* __restrict__ outb, float* __restrict__ outf) {
  int tid = threadIdx.x;
  int wave = tid >> 6, lane = tid & 63, l15 = lane & 15, kg = lane >> 4;
  f32x4 acc[4][2] = {};
  int ar = tid >> 2, ag = tid & 3;
  int aswz = ag ^ ((ar >> 1) & 3);
  for (int k0 = 0; k0 < K; k0 += 32) {
    uint4 av = *(const uint4*)(A + (size_t)(m0 + ar) * lda + k0 + ag * 8);
    *(uint4*)(&As[ar * 32 + aswz * 8]) = av;
#pragma unroll
    for (int i = 0; i < 2; i++) {
      int c = tid + i * 256;
      int br = c >> 2, bg = c & 3;
      int bswz = bg ^ ((br >> 1) & 3);
      uint4 bv = *(const uint4*)(BT + (size_t)(n0 + br) * ldb + k0 + bg * 8);
      *(uint4*)(&Bs[br * 32 + bswz * 8]) = bv;
    }
    __syncthreads();
    bf16x8 af[4], bfr[2];
#pragma unroll
    for (int mt = 0; mt < 4; mt++) {
      int row = mt * 16 + l15;
      int swz = kg ^ ((row >> 1) & 3);
      af[mt] = *(const bf16x8*)(&As[row * 32 + swz * 8]);
    }
#pragma unroll
    for (int nt = 0; nt < 2; nt++) {
      int row = wave * 32 + nt * 16 + l15;
      int swz = kg ^ ((row >> 1) & 3);
      bfr[nt] = *(const bf16x8*)(&Bs[row * 32 + swz * 8]);
    }
#pragma unroll
    for (int mt = 0; mt < 4; mt++)
#pragma unroll
      for (int nt = 0; nt < 2; nt++)
        acc[mt][nt] = __builtin_amdgcn_mfma_f32_16x16x32_bf16(af[mt], bfr[nt], acc[mt][nt], 0, 0, 0);
    __syncthreads();
  }
#pragma unroll
  for (int nt = 0; nt < 2; nt++) {
    int col = n0 + wave * 32 + nt * 16 + l15;
    float bsum = (EPI == 0) ? (bias1[col] + bias2[col]) : bias1[col];
#pragma unroll
    for (int mt = 0; mt < 4; mt++) {
#pragma unroll
      for (int r = 0; r < 4; r++) {
        int rowm = m0 + mt * 16 + kg * 4 + r;
        float v = acc[mt][nt][r] + bsum;
        if (EPI == 3) outf[(size_t)rowm * 1024 + col] = v;
        else outb[(size_t)rowm * 1024 + col] = f2bf(v);
      }
    }
  }
}

// 64x64-tile y-GEMM job (narrowed from validated mapping), fused col stats
__device__ void ygemm_job(ushort_t* As, ushort_t* Bs, int m0, int n0,
                          const ushort_t* __restrict__ A,
                          const ushort_t* __restrict__ BT,
                          const float* __restrict__ bias1,
                          ushort_t* __restrict__ outb, float* __restrict__ stats) {
  int tid = threadIdx.x;
  int wave = tid >> 6, lane = tid & 63, l15 = lane & 15, kg = lane >> 4;
  f32x4 acc[4] = {};
  int ar = tid >> 2, ag = tid & 3;
  int aswz = ag ^ ((ar >> 1) & 3);
  for (int k0 = 0; k0 < 1024; k0 += 32) {
    uint4 av = *(const uint4*)(A + (size_t)(m0 + ar) * 1024 + k0 + ag * 8);
    *(uint4*)(&As[ar * 32 + aswz * 8]) = av;
    {
      int br = tid >> 2, bg = tid & 3;              // 64 rows x 4 chunks
      int bswz = bg ^ ((br >> 1) & 3);
      uint4 bv = *(const uint4*)(BT + (size_t)(n0 + br) * 1024 + k0 + bg * 8);
      *(uint4*)(&Bs[br * 32 + bswz * 8]) = bv;
    }
    __syncthreads();
    bf16x8 af[4], bfr;
#pragma unroll
    for (int mt = 0; mt < 4; mt++) {
      int row = mt * 16 + l15;
      int swz = kg ^ ((row >> 1) & 3);
      af[mt] = *(const bf16x8*)(&As[row * 32 + swz * 8]);
    }
    {
      int row = wave * 16 + l15;
      int swz = kg ^ ((row >> 1) & 3);
      bfr = *(const bf16x8*)(&Bs[row * 32 + swz * 8]);
    }
#pragma unroll
    for (int mt = 0; mt < 4; mt++)
      acc[mt] = __builtin_amdgcn_mfma_f32_16x16x32_bf16(af[mt], bfr, acc[mt], 0, 0, 0);
    __syncthreads();
  }
  int col = n0 + wave * 16 + l15;
  float bsum = bias1[col];
  float s1 = 0.0f, s2 = 0.0f;
#pragma unroll
  for (int mt = 0; mt < 4; mt++) {
#pragma unroll
    for (int r = 0; r < 4; r++) {
      int rowm = m0 + mt * 16 + kg * 4 + r;
      float v = acc[mt][r] + bsum;
      outb[(size_t)rowm * 1024 + col] = f2bf(v);
      s1 += v; s2 = fmaf(v, v, s2);
    }
  }
  s1 += __shfl_down(s1, 16); s2 += __shfl_down(s2, 16);
  s1 += __shfl_down(s1, 32); s2 += __shfl_down(s2, 32);
  if (lane < 16) {
    atomicAdd(&stats[col], s1);
    atomicAdd(&stats[1024 + col], s2);
  }
}

// validated ectx (rank-1 pool update)
__device__ void ectx_job(int pbase, const float* occ, const float* Wenc,
                         const float* wfull, const float* w0, const float* P1,
                         const ushort_t* hd, ushort_t* pool) {
  int wave = threadIdx.x >> 6, lane = threadIdx.x & 63;
  int p = pbase + wave;
  __shared__ float occ_sh[4][64];
  occ_sh[wave][lane] = occ[p * 64 + lane];
  float hdv[16], we[16], wf[16];
#pragma unroll
  for (int j = 0; j < 16; j++) {
    int a = lane + j * 64;
    hdv[j] = bf2f(hd[(size_t)p * 1024 + a]);
    we[j] = Wenc[a];
    wf[j] = wfull[a];
  }
  float e_mine = 0.0f;
  for (int g = 0; g < 64; g++) {
    float c = occ_sh[wave][g];
    float s = 0.0f;
#pragma unroll
    for (int j = 0; j < 16; j++)
      s += fmaxf(fmaf(c, we[j], hdv[j]), 0.0f) * wf[j];
#pragma unroll
    for (int off = 32; off > 0; off >>= 1) s += __shfl_xor(s, off);
    if (lane == g) e_mine = s;
  }
  float m = e_mine;
#pragma unroll
  for (int off = 32; off > 0; off >>= 1) m = fmaxf(m, __shfl_xor(m, off));
  float xe = __expf(e_mine - m);
  float den = xe;
#pragma unroll
  for (int off = 32; off > 0; off >>= 1) den += __shfl_xor(den, off);
  float cp = xe * occ_sh[wave][lane];
#pragma unroll
  for (int off = 32; off > 0; off >>= 1) cp += __shfl_xor(cp, off);
  float ctx = cp / den;
#pragma unroll
  for (int j = 0; j < 16; j++) {
    int a = lane + j * 64;
    pool[(size_t)p * 1024 + a] = f2bf(fmaf(ctx, w0[a], P1[(size_t)p * 1024 + a]));
  }
}

// validated norm job
__device__ void norm_job(int j, int fl, const ushort_t* y_mf, const float* stats,
                         const float* gamma, const float* beta, void* out) {
  int idx = (j * 256 + threadIdx.x) * 4;
  int col = idx & 1023;
  float vv[4];
#pragma unroll
  for (int q = 0; q < 4; q++) vv[q] = bf2f(y_mf[idx + q]);
  float4 s1 = *(const float4*)(stats + col);
  float4 s2 = *(const float4*)(stats + 1024 + col);
  float4 gm = *(const float4*)(gamma + col);
  float4 bt = *(const float4*)(beta + col);
  const float ib = 1.0f / 2048.0f;
  float m1[4] = {s1.x, s1.y, s1.z, s1.w};
  float m2[4] = {s2.x, s2.y, s2.z, s2.w};
  float gg[4] = {gm.x, gm.y, gm.z, gm.w};
  float bb[4] = {bt.x, bt.y, bt.z, bt.w};
  float o[4];
#pragma unroll
  for (int q = 0; q < 4; q++) {
    float mu = m1[q] * ib;
    float var = fmaf(-mu, mu, m2[q] * ib);
    o[q] = fmaxf(fmaf(gg[q] * (vv[q] - mu), rsqrtf(var + 1e-5f), bb[q]), 0.0f);
  }
  if (fl) {
    ushort4 ov = make_ushort4(f2bf(o[0]), f2bf(o[1]), f2bf(o[2]), f2bf(o[3]));
    *(ushort4*)((ushort_t*)out + idx) = ov;
  } else {
    *(float4*)((float*)out + idx) = make_float4(o[0], o[1], o[2], o[3]);
  }
}

// ---------------------------------------------------------------- mega kernel
__global__ __launch_bounds__(256, 2) void k_mega(
    PrepPtrs ptrs, float* __restrict__ ws, unsigned* __restrict__ cnt,
    ushort_t* __restrict__ dout) {
  float* conv   = ws;
  float* c_Wenc = conv + 270336;
  float* c_benc = conv + 271360;
  float* c_bdec = conv + 272384;
  float* c_wful = conv + 273408;
  float* c_bout = conv + 274432;
  float* c_bmlp = conv + 275456;
  float* c_gam  = conv + 276480;
  float* c_bet  = conv + 277504;
  float* c_w0   = conv + 278528;
  float* occ    = ws + 280576;
  float* stats  = ws + 411648;
  float* P1     = ws + 413696;
  ushort_t* u0    = (ushort_t*)(ws + 2510848);
  ushort_t* hbf   = u0;
  ushort_t* WdecT = u0 + 131072;
  ushort_t* WoutT = u0 + 196608;
  ushort_t* WmlpT = u0 + 294912;
  ushort_t* Xcat0 = u0 + 1343488;
  ushort_t* y_mf  = u0 + 1540096;

  __shared__ ushort_t As[64 * 32];
  __shared__ ushort_t Bs[128 * 32];

  // dtype flag from first 256 halfwords of h (validated detector, 256 samples)
  __shared__ int bad_sh;
  if (threadIdx.x == 0) bad_sh = 0;
  __syncthreads();
  {
    float v = bf2f(((const ushort_t*)ptrs.p[0])[threadIdx.x]);
    if (!(fabsf(v) <= 1e4f)) atomicOr(&bad_sh, 1);
  }
  __syncthreads();
  int fl = (bad_sh == 0) ? 1 : 0;

  int bid = blockIdx.x;

  // ---- stage 0: prep (3826 jobs)
  for (int j = bid; j < 3826; j += NBLK) {
    prep_job(ptrs, fl, j, conv, hbf, WdecT, WoutT, WmlpT, Xcat0, occ, stats);
    __syncthreads();
  }
  gbar(cnt, NBLK);

  // ---- stage 1: gemm2 (512 jobs: z=job>>8, x=job&31, y=(job>>5)&7)
  {
    int m0 = (bid & 31) * 64, n0 = ((bid >> 5) & 7) * 128;
    if ((bid >> 8) == 0)
      mgemm_body<64, 0>(As, Bs, m0, n0, hbf, 64, WdecT, 64, c_benc, c_bdec,
                        dout, nullptr);
    else
      mgemm_body<96, 3>(As, Bs, m0, n0, Xcat0, 96, WoutT, 96, c_bout, nullptr,
                        nullptr, P1);
  }
  gbar(cnt, 2 * NBLK);

  // ---- stage 2: ectx (512 jobs)
  ectx_job(bid * 4, occ, c_Wenc, c_wful, c_w0, P1, dout, dout);
  gbar(cnt, 3 * NBLK);

  // ---- stage 3: y GEMM 64x64 (512 jobs: m0=(job&31)*64, n0=(job>>5)*64)
  ygemm_job(As, Bs, (bid & 31) * 64, (bid >> 5) * 64, dout, WmlpT, c_bmlp,
            y_mf, stats);
  gbar(cnt, 4 * NBLK);

  // ---- stage 4: norm (2048 jobs)
  for (int j = bid; j < 2048; j += NBLK)
    norm_job(j, fl, y_mf, stats, c_gam, c_bet, dout);
}

// ---------------------------------------------------------------- launch
extern "C" void kernel_launch(void* const* d_in, const int* in_sizes, int n_in,
                              void* d_out, int out_size, void* d_ws, size_t ws_size,
                              hipStream_t stream) {
  float* ws = (float*)d_ws;
  unsigned* cnt = (unsigned*)((char*)d_ws + 17317888);

  PrepPtrs ptrs;
  ptrs.p[0] = d_in[0];   // h (h2b, Xcat0, flag)
  ptrs.p[1] = d_in[6];   // W_dec (tp)
  ptrs.p[2] = d_in[10];  // W_out (tp rows 1..68)
  ptrs.p[3] = d_in[12];  // W_mlp (tp)
  ptrs.p[4] = d_in[1];   // end_pos  (convert seg0, Xcat0, occupancy)
  ptrs.p[5] = d_in[2];   // rel_pos  (seg1, Xcat0)
  ptrs.p[6] = d_in[3];   // scene    (seg2, occupancy)
  ptrs.p[7] = d_in[4];   // W_enc    (seg3)
  ptrs.p[8] = d_in[5];   // b_enc    (seg4)
  ptrs.p[9] = d_in[7];   // b_dec    (seg5)
  ptrs.p[10] = d_in[8];  // w_full   (seg6)
  ptrs.p[11] = d_in[11]; // b_out    (seg7)
  ptrs.p[12] = d_in[13]; // b_mlp    (seg8)
  ptrs.p[13] = d_in[14]; // gamma    (seg9)
  ptrs.p[14] = d_in[15]; // beta     (seg10)
  ptrs.p[15] = d_in[10]; // W_out row 0 = w0 (seg11)

  hipMemsetAsync(cnt, 0, sizeof(unsigned), stream);

  k_mega<<<NBLK, 256, 0, stream>>>(ptrs, ws, cnt, (ushort_t*)d_out);
}

// Round 11
// 360.429 us; speedup vs baseline: 1.0150x; 1.0150x over previous
//
#include <hip/hip_runtime.h>
#include <hip/hip_bf16.h>

// Round 11: round-10 mega-kernel with the grid barrier fixed. Round 10's gbar
// polled with atomicAdd(cnt,0) (full RMW) -> 512 pollers serialized at the
// coherence point -> ~60us/barrier (285us kernel, VALUBusy 7%). Fix: arrive
// with one RMW, poll with device-scope atomic LOAD (no RMW), s_sleep(16).
// All stage bodies byte-identical to round 10 (validated, absmax 0.03125).
//   stage0 prep   : convert | h2b | tpWdec | tpWout' | tpWmlp | Xcat0 | occup | stats0
//   stage1 gemm2  : z0 hd -> bf16 d_out ; z1 P1 -> f32 ws
//   stage2 ectx   : softmax ctx; pool = bf16(P1 + ctx*w0) -> d_out
//   stage3 ygemm  : y = pool@Wmlp + bmlp (64x64 tiles) + fused col stats
//   stage4 norm   : batchnorm(axis0) + relu -> d_out

#define NG2  64
#define NPTS 4096
#define NBLK 512

typedef unsigned short ushort_t;
typedef __attribute__((ext_vector_type(8))) short bf16x8;
typedef __attribute__((ext_vector_type(4))) float f32x4;

struct PrepPtrs { const void* p[16]; };

__device__ __forceinline__ float bf2f(ushort_t u) {
  return __uint_as_float(((unsigned int)u) << 16);
}
__device__ __forceinline__ ushort_t f2bf(float f) {
  __hip_bfloat16 b = __float2bfloat16(f);
  return *reinterpret_cast<ushort_t*>(&b);
}
__device__ __forceinline__ float lde(const void* p, size_t i, int fl) {
  return fl ? bf2f(((const ushort_t*)p)[i]) : ((const float*)p)[i];
}

// grid barrier: one RMW to arrive, atomic-LOAD polling (no RMW serialization)
__device__ __forceinline__ void gbar(unsigned* cnt, unsigned want) {
  __syncthreads();
  if (threadIdx.x == 0) {
    __threadfence();   // release
    __hip_atomic_fetch_add(cnt, 1u, __ATOMIC_RELAXED, __HIP_MEMORY_SCOPE_AGENT);
    while (__hip_atomic_load(cnt, __ATOMIC_RELAXED, __HIP_MEMORY_SCOPE_AGENT) < want)
      __builtin_amdgcn_s_sleep(16);
    __threadfence();   // acquire
  }
  __syncthreads();
}

// ---------------------------------------------------------------- stage bodies
__device__ __forceinline__ void tp_body(const void* in, int fl, int job,
                                        int Kin, int Kpad, ushort_t* out) {
  __shared__ ushort_t t[32][40];
  int n0 = (job & 31) * 32, k0 = (job >> 5) * 32;
  int r = threadIdx.x >> 3, c4 = (threadIdx.x & 7) * 4;
  ushort4 v = make_ushort4(0, 0, 0, 0);
  if (k0 + r < Kin) {
    size_t off = (size_t)(k0 + r) * 1024 + n0 + c4;
    if (fl) {
      v = *(const ushort4*)((const ushort_t*)in + off);
    } else {
      float4 f = *(const float4*)((const float*)in + off);
      v = make_ushort4(f2bf(f.x), f2bf(f.y), f2bf(f.z), f2bf(f.w));
    }
  }
  *(ushort4*)(&t[r][c4]) = v;
  __syncthreads();
  int n = threadIdx.x >> 3, kk = (threadIdx.x & 7) * 4;
  ushort4 o = make_ushort4(t[kk][n], t[kk + 1][n], t[kk + 2][n], t[kk + 3][n]);
  *(ushort4*)(out + (size_t)(n0 + n) * Kpad + k0 + kk) = o;
}

// jobs: [0,273)convert [273,401)h2b [401,465)tpWdec [465,561)tpWout'
//       [561,1585)tpWmlp [1585,1777)Xcat0 [1777,3825)occupancy [3825]stats0
__device__ void prep_job(const PrepPtrs& ptrs, int fl, int b,
                         float* conv, ushort_t* hbf, ushort_t* WdecT,
                         ushort_t* WoutT, ushort_t* WmlpT, ushort_t* Xcat0,
                         float* occ, float* stats) {
  if (b < 273) {
    const int ends[12] = {4096, 8192, 270336, 271360, 272384, 273408,
                          274432, 275456, 276480, 277504, 278528, 279552};
    int idx = (b * 256 + threadIdx.x) * 4;
    int seg = 0, base = 0;
#pragma unroll
    for (int s = 0; s < 11; s++) {
      if (idx >= ends[s]) { seg = s + 1; base = ends[s]; }
    }
    int off = idx - base;
    float4 o;
    if (fl) {
      const unsigned int* src = (const unsigned int*)ptrs.p[4 + seg];
      uint2 u = *(const uint2*)(src + (off >> 1));
      o.x = __uint_as_float((u.x & 0xFFFFu) << 16);
      o.y = __uint_as_float(u.x & 0xFFFF0000u);
      o.z = __uint_as_float((u.y & 0xFFFFu) << 16);
      o.w = __uint_as_float(u.y & 0xFFFF0000u);
    } else {
      o = *(const float4*)((const float*)ptrs.p[4 + seg] + off);
    }
    *(float4*)(conv + idx) = o;
  } else if (b < 401) {
    int i = (b - 273) * 256 + threadIdx.x;
    if (fl) {
      ((ushort4*)hbf)[i] = ((const ushort4*)ptrs.p[0])[i];
    } else {
      float4 f = ((const float4*)ptrs.p[0])[i];
      ((ushort4*)hbf)[i] = make_ushort4(f2bf(f.x), f2bf(f.y), f2bf(f.z), f2bf(f.w));
    }
  } else if (b < 465) {
    tp_body(ptrs.p[1], fl, b - 401, 64, 64, WdecT);
  } else if (b < 561) {
    const void* wout1 = fl ? (const void*)((const ushort_t*)ptrs.p[2] + 1024)
                           : (const void*)((const float*)ptrs.p[2] + 1024);
    tp_body(wout1, fl, b - 465, 68, 96, WoutT);
  } else if (b < 1585) {
    tp_body(ptrs.p[3], fl, b - 561, 1024, 1024, WmlpT);
  } else if (b < 1777) {
    int flat = (b - 1585) * 256 + threadIdx.x;
    int e4 = flat * 4;
    int r = e4 / 96, c = e4 - r * 96;
    ushort4 v = make_ushort4(0, 0, 0, 0);
    if (c < 64) {
      if (fl) v = *(const ushort4*)((const ushort_t*)ptrs.p[0] + r * 64 + c);
      else {
        float4 f = *(const float4*)((const float*)ptrs.p[0] + r * 64 + c);
        v = make_ushort4(f2bf(f.x), f2bf(f.y), f2bf(f.z), f2bf(f.w));
      }
    } else if (c == 64) {
      v.x = f2bf(lde(ptrs.p[4], 2 * r, fl));
      v.y = f2bf(lde(ptrs.p[4], 2 * r + 1, fl));
      v.z = f2bf(lde(ptrs.p[5], 2 * r, fl));
      v.w = f2bf(lde(ptrs.p[5], 2 * r + 1, fl));
    }
    *(ushort4*)(Xcat0 + e4) = v;
  } else if (b < 3825) {
    int i = b - 1777;
    int s = i >> 6;
    __shared__ float cnth[NG2];
    if (threadIdx.x < NG2) cnth[threadIdx.x] = 0.0f;
    __syncthreads();
    float ex = lde(ptrs.p[4], 2 * i, fl), ey = lde(ptrs.p[4], 2 * i + 1, fl);
    float tlx = ex - 1.0f, tly = ey + 1.0f, brx = ex + 1.0f, bry = ey - 1.0f;
    const void* scn = ptrs.p[6];
    for (int p = threadIdx.x; p < NPTS; p += 256) {
      size_t o2 = (size_t)s * NPTS * 2 + 2 * p;
      float sx = lde(scn, o2, fl), sy = lde(scn, o2 + 1, fl);
      bool oob = (sx >= brx) || (sx <= tlx) || (sy >= tly) || (sy <= bry);
      if (!oob) {
        int cx = (int)floorf((sx - tlx) * 0.5f * 8.0f);
        int cy = (int)floorf((tly - sy) * 0.5f * 8.0f);
        int cell = cx + cy * 8;
        if (cell >= 0 && cell < NG2) atomicAdd(&cnth[cell], 1.0f);
      }
    }
    __syncthreads();
    if (threadIdx.x < NG2) occ[i * NG2 + threadIdx.x] = cnth[threadIdx.x];
  } else {
#pragma unroll
    for (int k = 0; k < 8; k++) stats[threadIdx.x + 256 * k] = 0.0f;
  }
}

// validated 64x128 MFMA body. EPI0: bf16(acc+b1+b2); EPI3: f32 acc+b1
template <int K, int EPI>
__device__ void mgemm_body(ushort_t* As, ushort_t* Bs, int m0, int n0,
                           const ushort_t* __restrict__ A, int lda,
                           const ushort_t* __restrict__ BT, int ldb,
                           const float* __restrict__ bias1, const float* __restrict__ bias2,
                           ushort_t* __restrict__ outb, float* __restrict__ outf) {
  int tid = threadIdx.x;
  int wave = tid >> 6, lane = tid & 63, l15 = lane & 15, kg = lane >> 4;
  f32x4 acc[4][2] = {};
  int ar = tid >> 2, ag = tid & 3;
  int aswz = ag ^ ((ar >> 1) & 3);
  for (int k0 = 0; k0 < K; k0 += 32) {
    uint4 av = *(const uint4*)(A + (size_t)(m0 + ar) * lda + k0 + ag * 8);
    *(uint4*)(&As[ar * 32 + aswz * 8]) = av;
#pragma unroll
    for (int i = 0; i < 2; i++) {
      int c = tid + i * 256;
      int br = c >> 2, bg = c & 3;
      int bswz = bg ^ ((br >> 1) & 3);
      uint4 bv = *(const uint4*)(BT + (size_t)(n0 + br) * ldb + k0 + bg * 8);
      *(uint4*)(&Bs[br * 32 + bswz * 8]) = bv;
    }
    __syncthreads();
    bf16x8 af[4], bfr[2];
#pragma unroll
    for (int mt = 0; mt < 4; mt++) {
      int row = mt * 16 + l15;
      int swz = kg ^ ((row >> 1) & 3);
      af[mt] = *(const bf16x8*)(&As[row * 32 + swz * 8]);
    }
#pragma unroll
    for (int nt = 0; nt < 2; nt++) {
      int row = wave * 32 + nt * 16 + l15;
      int swz = kg ^ ((row >> 1) & 3);
      bfr[nt] = *(const bf16x8*)(&Bs[row * 32 + swz * 8]);
    }
#pragma unroll
    for (int mt = 0; mt < 4; mt++)
#pragma unroll
      for (int nt = 0; nt < 2; nt++)
        acc[mt][nt] = __builtin_amdgcn_mfma_f32_16x16x32_bf16(af[mt], bfr[nt], acc[mt][nt], 0, 0, 0);
    __syncthreads();
  }
#pragma unroll
  for (int nt = 0; nt < 2; nt++) {
    int col = n0 + wave * 32 + nt * 16 + l15;
    float bsum = (EPI == 0) ? (bias1[col] + bias2[col]) : bias1[col];
#pragma unroll
    for (int mt = 0; mt < 4; mt++) {
#pragma unroll
      for (int r = 0; r < 4; r++) {
        int rowm = m0 + mt * 16 + kg * 4 + r;
        float v = acc[mt][nt][r] + bsum;
        if (EPI == 3) outf[(size_t)rowm * 1024 + col] = v;
        else outb[(size_t)rowm * 1024 + col] = f2bf(v);
      }
    }
  }
}

// 64x64-tile y-GEMM job, fused col stats (validated round 10)
__device__ void ygemm_job(ushort_t* As, ushort_t* Bs, int m0, int n0,
                          const ushort_t* __restrict__ A,
                          const ushort_t* __restrict__ BT,
                          const float* __restrict__ bias1,
                          ushort_t* __restrict__ outb, float* __restrict__ stats) {
  int tid = threadIdx.x;
  int wave = tid >> 6, lane = tid & 63, l15 = lane & 15, kg = lane >> 4;
  f32x4 acc[4] = {};
  int ar = tid >> 2, ag = tid & 3;
  int aswz = ag ^ ((ar >> 1) & 3);
  for (int k0 = 0; k0 < 1024; k0 += 32) {
    uint4 av = *(const uint4*)(A + (size_t)(m0 + ar) * 1024 + k0 + ag * 8);
    *(uint4*)(&As[ar * 32 + aswz * 8]) = av;
    {
      int br = tid >> 2, bg = tid & 3;
      int bswz = bg ^ ((br >> 1) & 3);
      uint4 bv = *(const uint4*)(BT + (size_t)(n0 + br) * 1024 + k0 + bg * 8);
      *(uint4*)(&Bs[br * 32 + bswz * 8]) = bv;
    }
    __syncthreads();
    bf16x8 af[4], bfr;
#pragma unroll
    for (int mt = 0; mt < 4; mt++) {
      int row = mt * 16 + l15;
      int swz = kg ^ ((row >> 1) & 3);
      af[mt] = *(const bf16x8*)(&As[row * 32 + swz * 8]);
    }
    {
      int row = wave * 16 + l15;
      int swz = kg ^ ((row >> 1) & 3);
      bfr = *(const bf16x8*)(&Bs[row * 32 + swz * 8]);
    }
#pragma unroll
    for (int mt = 0; mt < 4; mt++)
      acc[mt] = __builtin_amdgcn_mfma_f32_16x16x32_bf16(af[mt], bfr, acc[mt], 0, 0, 0);
    __syncthreads();
  }
  int col = n0 + wave * 16 + l15;
  float bsum = bias1[col];
  float s1 = 0.0f, s2 = 0.0f;
#pragma unroll
  for (int mt = 0; mt < 4; mt++) {
#pragma unroll
    for (int r = 0; r < 4; r++) {
      int rowm = m0 + mt * 16 + kg * 4 + r;
      float v = acc[mt][r] + bsum;
      outb[(size_t)rowm * 1024 + col] = f2bf(v);
      s1 += v; s2 = fmaf(v, v, s2);
    }
  }
  s1 += __shfl_down(s1, 16); s2 += __shfl_down(s2, 16);
  s1 += __shfl_down(s1, 32); s2 += __shfl_down(s2, 32);
  if (lane < 16) {
    atomicAdd(&stats[col], s1);
    atomicAdd(&stats[1024 + col], s2);
  }
}

// validated ectx (rank-1 pool update)
__device__ void ectx_job(int pbase, const float* occ, const float* Wenc,
                         const float* wfull, const float* w0, const float* P1,
                         const ushort_t* hd, ushort_t* pool) {
  int wave = threadIdx.x >> 6, lane = threadIdx.x & 63;
  int p = pbase + wave;
  __shared__ float occ_sh[4][64];
  occ_sh[wave][lane] = occ[p * 64 + lane];
  float hdv[16], we[16], wf[16];
#pragma unroll
  for (int j = 0; j < 16; j++) {
    int a = lane + j * 64;
    hdv[j] = bf2f(hd[(size_t)p * 1024 + a]);
    we[j] = Wenc[a];
    wf[j] = wfull[a];
  }
  float e_mine = 0.0f;
  for (int g = 0; g < 64; g++) {
    float c = occ_sh[wave][g];
    float s = 0.0f;
#pragma unroll
    for (int j = 0; j < 16; j++)
      s += fmaxf(fmaf(c, we[j], hdv[j]), 0.0f) * wf[j];
#pragma unroll
    for (int off = 32; off > 0; off >>= 1) s += __shfl_xor(s, off);
    if (lane == g) e_mine = s;
  }
  float m = e_mine;
#pragma unroll
  for (int off = 32; off > 0; off >>= 1) m = fmaxf(m, __shfl_xor(m, off));
  float xe = __expf(e_mine - m);
  float den = xe;
#pragma unroll
  for (int off = 32; off > 0; off >>= 1) den += __shfl_xor(den, off);
  float cp = xe * occ_sh[wave][lane];
#pragma unroll
  for (int off = 32; off > 0; off >>= 1) cp += __shfl_xor(cp, off);
  float ctx = cp / den;
#pragma unroll
  for (int j = 0; j < 16; j++) {
    int a = lane + j * 64;
    pool[(size_t)p * 1024 + a] = f2bf(fmaf(ctx, w0[a], P1[(size_t)p * 1024 + a]));
  }
}

// validated norm job
__device__ void norm_job(int j, int fl, const ushort_t* y_mf, const float* stats,
                         const float* gamma, const float* beta, void* out) {
  int idx = (j * 256 + threadIdx.x) * 4;
  int col = idx & 1023;
  float vv[4];
#pragma unroll
  for (int q = 0; q < 4; q++) vv[q] = bf2f(y_mf[idx + q]);
  float4 s1 = *(const float4*)(stats + col);
  float4 s2 = *(const float4*)(stats + 1024 + col);
  float4 gm = *(const float4*)(gamma + col);
  float4 bt = *(const float4*)(beta + col);
  const float ib = 1.0f / 2048.0f;
  float m1[4] = {s1.x, s1.y, s1.z, s1.w};
  float m2[4] = {s2.x, s2.y, s2.z, s2.w};
  float gg[4] = {gm.x, gm.y, gm.z, gm.w};
  float bb[4] = {bt.x, bt.y, bt.z, bt.w};
  float o[4];
#pragma unroll
  for (int q = 0; q < 4; q++) {
    float mu = m1[q] * ib;
    float var = fmaf(-mu, mu, m2[q] * ib);
    o[q] = fmaxf(fmaf(gg[q] * (vv[q] - mu), rsqrtf(var + 1e-5f), bb[q]), 0.0f);
  }
  if (fl) {
    ushort4 ov = make_ushort4(f2bf(o[0]), f2bf(o[1]), f2bf(o[2]), f2bf(o[3]));
    *(ushort4*)((ushort_t*)out + idx) = ov;
  } else {
    *(float4*)((float*)out + idx) = make_float4(o[0], o[1], o[2], o[3]);
  }
}

// ---------------------------------------------------------------- mega kernel
__global__ __launch_bounds__(256, 2) void k_mega(
    PrepPtrs ptrs, float* __restrict__ ws, unsigned* __restrict__ cnt,
    ushort_t* __restrict__ dout) {
  float* conv   = ws;
  float* c_Wenc = conv + 270336;
  float* c_benc = conv + 271360;
  float* c_bdec = conv + 272384;
  float* c_wful = conv + 273408;
  float* c_bout = conv + 274432;
  float* c_bmlp = conv + 275456;
  float* c_gam  = conv + 276480;
  float* c_bet  = conv + 277504;
  float* c_w0   = conv + 278528;
  float* occ    = ws + 280576;
  float* stats  = ws + 411648;
  float* P1     = ws + 413696;
  ushort_t* u0    = (ushort_t*)(ws + 2510848);
  ushort_t* hbf   = u0;
  ushort_t* WdecT = u0 + 131072;
  ushort_t* WoutT = u0 + 196608;
  ushort_t* WmlpT = u0 + 294912;
  ushort_t* Xcat0 = u0 + 1343488;
  ushort_t* y_mf  = u0 + 1540096;

  __shared__ ushort_t As[64 * 32];
  __shared__ ushort_t Bs[128 * 32];

  __shared__ int bad_sh;
  if (threadIdx.x == 0) bad_sh = 0;
  __syncthreads();
  {
    float v = bf2f(((const ushort_t*)ptrs.p[0])[threadIdx.x]);
    if (!(fabsf(v) <= 1e4f)) atomicOr(&bad_sh, 1);
  }
  __syncthreads();
  int fl = (bad_sh == 0) ? 1 : 0;

  int bid = blockIdx.x;

  // ---- stage 0: prep (3826 jobs)
  for (int j = bid; j < 3826; j += NBLK) {
    prep_job(ptrs, fl, j, conv, hbf, WdecT, WoutT, WmlpT, Xcat0, occ, stats);
    __syncthreads();
  }
  gbar(cnt, NBLK);

  // ---- stage 1: gemm2 (512 jobs)
  {
    int m0 = (bid & 31) * 64, n0 = ((bid >> 5) & 7) * 128;
    if ((bid >> 8) == 0)
      mgemm_body<64, 0>(As, Bs, m0, n0, hbf, 64, WdecT, 64, c_benc, c_bdec,
                        dout, nullptr);
    else
      mgemm_body<96, 3>(As, Bs, m0, n0, Xcat0, 96, WoutT, 96, c_bout, nullptr,
                        nullptr, P1);
  }
  gbar(cnt, 2 * NBLK);

  // ---- stage 2: ectx (512 jobs)
  ectx_job(bid * 4, occ, c_Wenc, c_wful, c_w0, P1, dout, dout);
  gbar(cnt, 3 * NBLK);

  // ---- stage 3: y GEMM 64x64 (512 jobs)
  ygemm_job(As, Bs, (bid & 31) * 64, (bid >> 5) * 64, dout, WmlpT, c_bmlp,
            y_mf, stats);
  gbar(cnt, 4 * NBLK);

  // ---- stage 4: norm (2048 jobs)
  for (int j = bid; j < 2048; j += NBLK)
    norm_job(j, fl, y_mf, stats, c_gam, c_bet, dout);
}

// ---------------------------------------------------------------- launch
extern "C" void kernel_launch(void* const* d_in, const int* in_sizes, int n_in,
                              void* d_out, int out_size, void* d_ws, size_t ws_size,
                              hipStream_t stream) {
  float* ws = (float*)d_ws;
  unsigned* cnt = (unsigned*)((char*)d_ws + 17317888);

  PrepPtrs ptrs;
  ptrs.p[0] = d_in[0];   // h (h2b, Xcat0, flag)
  ptrs.p[1] = d_in[6];   // W_dec (tp)
  ptrs.p[2] = d_in[10];  // W_out (tp rows 1..68)
  ptrs.p[3] = d_in[12];  // W_mlp (tp)
  ptrs.p[4] = d_in[1];   // end_pos  (convert seg0, Xcat0, occupancy)
  ptrs.p[5] = d_in[2];   // rel_pos  (seg1, Xcat0)
  ptrs.p[6] = d_in[3];   // scene    (seg2, occupancy)
  ptrs.p[7] = d_in[4];   // W_enc    (seg3)
  ptrs.p[8] = d_in[5];   // b_enc    (seg4)
  ptrs.p[9] = d_in[7];   // b_dec    (seg5)
  ptrs.p[10] = d_in[8];  // w_full   (seg6)
  ptrs.p[11] = d_in[11]; // b_out    (seg7)
  ptrs.p[12] = d_in[13]; // b_mlp    (seg8)
  ptrs.p[13] = d_in[14]; // gamma    (seg9)
  ptrs.p[14] = d_in[15]; // beta     (seg10)
  ptrs.p[15] = d_in[10]; // W_out row 0 = w0 (seg11)

  hipMemsetAsync(cnt, 0, sizeof(unsigned), stream);

  k_mega<<<NBLK, 256, 0, stream>>>(ptrs, ws, cnt, (ushort_t*)d_out);
}

// Round 12
// 162.643 us; speedup vs baseline: 2.2494x; 2.2161x over previous
//
#include <hip/hip_runtime.h>
#include <hip/hip_bf16.h>

// Round 12: revert to validated round-9 5-dispatch pipeline (163.6 us), plus:
//  (a) convert trimmed to the 9 live 1024-float segments (end/rel/scene were
//      dead: occupancy + Xcat0 read d_in raw) -> prep grid 3826 -> 3562
//  (b) y-GEMM re-tiled 64x64 x 512 blocks (2/CU; job body numerically
//      validated in rounds 10/11, absmax identical)
// Mega-kernel abandoned: device-scope fences for a software grid barrier cost
// ~60us each on 8-XCD gfx950 (L2 wb/inv at the coherence point); kernel
// boundaries do the same for ~2.4us.
//
// ws (floats): conv 0..9216 (Wenc0 benc1024 bdec2048 wful3072 bout4096
//   bmlp5120 gam6144 bet7168 w0 8192) | occ@9216(131072) | stats@140288(2048)
//   | P1@142336(2097152)
// bf16 u0=(ushort*)(ws+2239488): hbf0 WdecT@131072 WoutT@196608 WmlpT@294912
//   Xcat0@1343488 y_mf@1540096..3637248   (~16.2 MB)
// hd / pool staged in d_out (validated; rewritten by k_norm).

#define NG2  64
#define NPTS 4096

typedef unsigned short ushort_t;
typedef __attribute__((ext_vector_type(8))) short bf16x8;
typedef __attribute__((ext_vector_type(4))) float f32x4;

struct PrepPtrs { const void* p[16]; };

__device__ __forceinline__ float bf2f(ushort_t u) {
  return __uint_as_float(((unsigned int)u) << 16);
}
__device__ __forceinline__ ushort_t f2bf(float f) {
  __hip_bfloat16 b = __float2bfloat16(f);
  return *reinterpret_cast<ushort_t*>(&b);
}
__device__ __forceinline__ float lde(const void* p, size_t i, int fl) {
  return fl ? bf2f(((const ushort_t*)p)[i]) : ((const float*)p)[i];
}
__device__ __forceinline__ int block_flag(const ushort_t* h) {
  __shared__ int bad_sh;
  if (threadIdx.x == 0) bad_sh = 0;
  __syncthreads();
  float v = bf2f(h[threadIdx.x & 255]);
  if (!(fabsf(v) <= 1e4f)) atomicOr(&bad_sh, 1);
  __syncthreads();
  return (bad_sh == 0) ? 1 : 0;
}

// ---------------------------------------------------------------- fused prep
// [0,9)convert  [9,137)h2b  [137,201)tpWdec  [201,297)tpWout'(rows1..68)
// [297,1321)tpWmlp  [1321,1513)Xcat0  [1513,3561)occupancy  [3561]stats0
__device__ __forceinline__ void tp_body(const void* in, int fl, int job,
                                        int Kin, int Kpad, ushort_t* out) {
  __shared__ ushort_t t[32][40];
  int n0 = (job & 31) * 32, k0 = (job >> 5) * 32;
  int r = threadIdx.x >> 3, c4 = (threadIdx.x & 7) * 4;
  ushort4 v = make_ushort4(0, 0, 0, 0);
  if (k0 + r < Kin) {
    size_t off = (size_t)(k0 + r) * 1024 + n0 + c4;
    if (fl) {
      v = *(const ushort4*)((const ushort_t*)in + off);
    } else {
      float4 f = *(const float4*)((const float*)in + off);
      v = make_ushort4(f2bf(f.x), f2bf(f.y), f2bf(f.z), f2bf(f.w));
    }
  }
  *(ushort4*)(&t[r][c4]) = v;
  __syncthreads();
  int n = threadIdx.x >> 3, kk = (threadIdx.x & 7) * 4;
  ushort4 o = make_ushort4(t[kk][n], t[kk + 1][n], t[kk + 2][n], t[kk + 3][n]);
  *(ushort4*)(out + (size_t)(n0 + n) * Kpad + k0 + kk) = o;
}

__global__ __launch_bounds__(256) void k_prep(PrepPtrs ptrs,
                                              float* __restrict__ conv,
                                              ushort_t* __restrict__ hbf,
                                              ushort_t* __restrict__ WdecT,
                                              ushort_t* __restrict__ WoutT,
                                              ushort_t* __restrict__ WmlpT,
                                              ushort_t* __restrict__ Xcat0,
                                              float* __restrict__ occ,
                                              float* __restrict__ stats) {
  int b = blockIdx.x;
  int fl = block_flag((const ushort_t*)ptrs.p[0]);
  if (b < 9) {
    // 9 segments x 1024 floats: Wenc benc bdec wful bout bmlp gam bet w0
    int idx = (b * 256 + threadIdx.x) * 4;
    int seg = idx >> 10, off = idx & 1023;
    float4 o;
    if (fl) {
      const unsigned int* src = (const unsigned int*)ptrs.p[7 + seg];
      uint2 u = *(const uint2*)(src + (off >> 1));
      o.x = __uint_as_float((u.x & 0xFFFFu) << 16);
      o.y = __uint_as_float(u.x & 0xFFFF0000u);
      o.z = __uint_as_float((u.y & 0xFFFFu) << 16);
      o.w = __uint_as_float(u.y & 0xFFFF0000u);
    } else {
      o = *(const float4*)((const float*)ptrs.p[7 + seg] + off);
    }
    *(float4*)(conv + idx) = o;
  } else if (b < 137) {
    int i = (b - 9) * 256 + threadIdx.x;   // 32768 x4 items
    if (fl) {
      ((ushort4*)hbf)[i] = ((const ushort4*)ptrs.p[0])[i];
    } else {
      float4 f = ((const float4*)ptrs.p[0])[i];
      ((ushort4*)hbf)[i] = make_ushort4(f2bf(f.x), f2bf(f.y), f2bf(f.z), f2bf(f.w));
    }
  } else if (b < 201) {
    tp_body(ptrs.p[1], fl, b - 137, 64, 64, WdecT);
  } else if (b < 297) {
    const void* wout1 = fl ? (const void*)((const ushort_t*)ptrs.p[2] + 1024)
                           : (const void*)((const float*)ptrs.p[2] + 1024);
    tp_body(wout1, fl, b - 201, 68, 96, WoutT);
  } else if (b < 1321) {
    tp_body(ptrs.p[3], fl, b - 297, 1024, 1024, WmlpT);
  } else if (b < 1513) {
    int flat = (b - 1321) * 256 + threadIdx.x;   // 49152 ushort4 items
    int e4 = flat * 4;
    int r = e4 / 96, c = e4 - r * 96;
    ushort4 v = make_ushort4(0, 0, 0, 0);
    if (c < 64) {
      if (fl) v = *(const ushort4*)((const ushort_t*)ptrs.p[0] + r * 64 + c);
      else {
        float4 f = *(const float4*)((const float*)ptrs.p[0] + r * 64 + c);
        v = make_ushort4(f2bf(f.x), f2bf(f.y), f2bf(f.z), f2bf(f.w));
      }
    } else if (c == 64) {
      v.x = f2bf(lde(ptrs.p[4], 2 * r, fl));      // end x
      v.y = f2bf(lde(ptrs.p[4], 2 * r + 1, fl));  // end y
      v.z = f2bf(lde(ptrs.p[5], 2 * r, fl));      // rel x
      v.w = f2bf(lde(ptrs.p[5], 2 * r + 1, fl));  // rel y
    }
    *(ushort4*)(Xcat0 + e4) = v;
  } else if (b < 3561) {
    int i = b - 1513;
    int s = i >> 6;
    __shared__ float cnth[NG2];
    if (threadIdx.x < NG2) cnth[threadIdx.x] = 0.0f;
    __syncthreads();
    float ex = lde(ptrs.p[4], 2 * i, fl), ey = lde(ptrs.p[4], 2 * i + 1, fl);
    float tlx = ex - 1.0f, tly = ey + 1.0f, brx = ex + 1.0f, bry = ey - 1.0f;
    const void* scn = ptrs.p[6];
    for (int p = threadIdx.x; p < NPTS; p += 256) {
      size_t o2 = (size_t)s * NPTS * 2 + 2 * p;
      float sx = lde(scn, o2, fl), sy = lde(scn, o2 + 1, fl);
      bool oob = (sx >= brx) || (sx <= tlx) || (sy >= tly) || (sy <= bry);
      if (!oob) {
        int cx = (int)floorf((sx - tlx) * 0.5f * 8.0f);
        int cy = (int)floorf((tly - sy) * 0.5f * 8.0f);
        int cell = cx + cy * 8;
        if (cell >= 0 && cell < NG2) atomicAdd(&cnth[cell], 1.0f);
      }
    }
    __syncthreads();
    if (threadIdx.x < NG2) occ[i * NG2 + threadIdx.x] = cnth[threadIdx.x];
  } else {
#pragma unroll
    for (int k = 0; k < 8; k++) stats[threadIdx.x + 256 * k] = 0.0f;
  }
}

// ---------------------------------------------------------------- MFMA GEMM body (validated)
// EPI0: bf16(acc + b1 + b2) ; EPI3: f32 acc + b1
template <int K, int EPI>
__device__ __forceinline__ void mgemm_body(
    ushort_t* As, ushort_t* Bs, int m0, int n0,
    const ushort_t* __restrict__ A, int lda,
    const ushort_t* __restrict__ BT, int ldb,
    const float* __restrict__ bias1, const float* __restrict__ bias2,
    ushort_t* __restrict__ outb, float* __restrict__ outf) {
  int tid = threadIdx.x;
  int wave = tid >> 6, lane = tid & 63, l15 = lane & 15, kg = lane >> 4;
  f32x4 acc[4][2] = {};
  int ar = tid >> 2, ag = tid & 3;
  int aswz = ag ^ ((ar >> 1) & 3);
  for (int k0 = 0; k0 < K; k0 += 32) {
    uint4 av = *(const uint4*)(A + (size_t)(m0 + ar) * lda + k0 + ag * 8);
    *(uint4*)(&As[ar * 32 + aswz * 8]) = av;
#pragma unroll
    for (int i = 0; i < 2; i++) {
      int c = tid + i * 256;
      int br = c >> 2, bg = c & 3;
      int bswz = bg ^ ((br >> 1) & 3);
      uint4 bv = *(const uint4*)(BT + (size_t)(n0 + br) * ldb + k0 + bg * 8);
      *(uint4*)(&Bs[br * 32 + bswz * 8]) = bv;
    }
    __syncthreads();
    bf16x8 af[4], bfr[2];
#pragma unroll
    for (int mt = 0; mt < 4; mt++) {
      int row = mt * 16 + l15;
      int swz = kg ^ ((row >> 1) & 3);
      af[mt] = *(const bf16x8*)(&As[row * 32 + swz * 8]);
    }
#pragma unroll
    for (int nt = 0; nt < 2; nt++) {
      int row = wave * 32 + nt * 16 + l15;
      int swz = kg ^ ((row >> 1) & 3);
      bfr[nt] = *(const bf16x8*)(&Bs[row * 32 + swz * 8]);
    }
#pragma unroll
    for (int mt = 0; mt < 4; mt++)
#pragma unroll
      for (int nt = 0; nt < 2; nt++)
        acc[mt][nt] = __builtin_amdgcn_mfma_f32_16x16x32_bf16(af[mt], bfr[nt], acc[mt][nt], 0, 0, 0);
    __syncthreads();
  }
#pragma unroll
  for (int nt = 0; nt < 2; nt++) {
    int col = n0 + wave * 32 + nt * 16 + l15;
    float bsum = (EPI == 0) ? (bias1[col] + bias2[col]) : bias1[col];
#pragma unroll
    for (int mt = 0; mt < 4; mt++) {
#pragma unroll
      for (int r = 0; r < 4; r++) {
        int rowm = m0 + mt * 16 + kg * 4 + r;
        float v = acc[mt][nt][r] + bsum;
        if (EPI == 3) outf[(size_t)rowm * 1024 + col] = v;
        else outb[(size_t)rowm * 1024 + col] = f2bf(v);
      }
    }
  }
}

// z=0: hd (K=64) -> bf16 d_out ; z=1: P1 (K=96) -> f32 ws   (round-9 validated)
__global__ __launch_bounds__(256) void k_gemm2(
    const ushort_t* __restrict__ hbf, const ushort_t* __restrict__ WdecT,
    const float* __restrict__ benc, const float* __restrict__ bdec,
    ushort_t* __restrict__ hd_out,
    const ushort_t* __restrict__ Xcat0, const ushort_t* __restrict__ WoutT,
    const float* __restrict__ bout, float* __restrict__ P1) {
  __shared__ ushort_t As[64 * 32];
  __shared__ ushort_t Bs[128 * 32];
  int m0 = blockIdx.x * 64, n0 = blockIdx.y * 128;
  if (blockIdx.z == 0)
    mgemm_body<64, 0>(As, Bs, m0, n0, hbf, 64, WdecT, 64, benc, bdec, hd_out, nullptr);
  else
    mgemm_body<96, 3>(As, Bs, m0, n0, Xcat0, 96, WoutT, 96, bout, nullptr, nullptr, P1);
}

// ---------------------------------------------------------------- y GEMM 64x64 (validated r10/11)
__global__ __launch_bounds__(256) void k_ygemm(
    const ushort_t* __restrict__ A, const ushort_t* __restrict__ BT,
    const float* __restrict__ bias1, ushort_t* __restrict__ outb,
    float* __restrict__ stats) {
  __shared__ ushort_t As[64 * 32];
  __shared__ ushort_t Bs[64 * 32];
  int m0 = blockIdx.x * 64, n0 = blockIdx.y * 64;
  int tid = threadIdx.x;
  int wave = tid >> 6, lane = tid & 63, l15 = lane & 15, kg = lane >> 4;
  f32x4 acc[4] = {};
  int ar = tid >> 2, ag = tid & 3;
  int aswz = ag ^ ((ar >> 1) & 3);
  for (int k0 = 0; k0 < 1024; k0 += 32) {
    uint4 av = *(const uint4*)(A + (size_t)(m0 + ar) * 1024 + k0 + ag * 8);
    *(uint4*)(&As[ar * 32 + aswz * 8]) = av;
    {
      int br = tid >> 2, bg = tid & 3;
      int bswz = bg ^ ((br >> 1) & 3);
      uint4 bv = *(const uint4*)(BT + (size_t)(n0 + br) * 1024 + k0 + bg * 8);
      *(uint4*)(&Bs[br * 32 + bswz * 8]) = bv;
    }
    __syncthreads();
    bf16x8 af[4], bfr;
#pragma unroll
    for (int mt = 0; mt < 4; mt++) {
      int row = mt * 16 + l15;
      int swz = kg ^ ((row >> 1) & 3);
      af[mt] = *(const bf16x8*)(&As[row * 32 + swz * 8]);
    }
    {
      int row = wave * 16 + l15;
      int swz = kg ^ ((row >> 1) & 3);
      bfr = *(const bf16x8*)(&Bs[row * 32 + swz * 8]);
    }
#pragma unroll
    for (int mt = 0; mt < 4; mt++)
      acc[mt] = __builtin_amdgcn_mfma_f32_16x16x32_bf16(af[mt], bfr, acc[mt], 0, 0, 0);
    __syncthreads();
  }
  int col = n0 + wave * 16 + l15;
  float bsum = bias1[col];
  float s1 = 0.0f, s2 = 0.0f;
#pragma unroll
  for (int mt = 0; mt < 4; mt++) {
#pragma unroll
    for (int r = 0; r < 4; r++) {
      int rowm = m0 + mt * 16 + kg * 4 + r;
      float v = acc[mt][r] + bsum;
      outb[(size_t)rowm * 1024 + col] = f2bf(v);
      s1 += v; s2 = fmaf(v, v, s2);
    }
  }
  s1 += __shfl_down(s1, 16); s2 += __shfl_down(s2, 16);
  s1 += __shfl_down(s1, 32); s2 += __shfl_down(s2, 32);
  if (lane < 16) {
    atomicAdd(&stats[col], s1);
    atomicAdd(&stats[1024 + col], s2);
  }
}

// ---------------------------------------------------------------- ectx (round-9 validated)
__global__ __launch_bounds__(256) void k_ectx(
    const float* __restrict__ occ,
    const float* __restrict__ Wenc, const float* __restrict__ wfull,
    const float* __restrict__ w0, const float* __restrict__ P1,
    const ushort_t* __restrict__ hd, ushort_t* __restrict__ pool) {
  int wave = threadIdx.x >> 6, lane = threadIdx.x & 63;
  int p = blockIdx.x * 4 + wave;
  __shared__ float occ_sh[4][64];
  occ_sh[wave][lane] = occ[p * 64 + lane];
  float hdv[16], we[16], wf[16];
#pragma unroll
  for (int j = 0; j < 16; j++) {
    int a = lane + j * 64;
    hdv[j] = bf2f(hd[(size_t)p * 1024 + a]);
    we[j] = Wenc[a];
    wf[j] = wfull[a];
  }
  float e_mine = 0.0f;
  for (int g = 0; g < 64; g++) {
    float c = occ_sh[wave][g];
    float s = 0.0f;
#pragma unroll
    for (int j = 0; j < 16; j++)
      s += fmaxf(fmaf(c, we[j], hdv[j]), 0.0f) * wf[j];
#pragma unroll
    for (int off = 32; off > 0; off >>= 1) s += __shfl_xor(s, off);
    if (lane == g) e_mine = s;
  }
  float m = e_mine;
#pragma unroll
  for (int off = 32; off > 0; off >>= 1) m = fmaxf(m, __shfl_xor(m, off));
  float xe = __expf(e_mine - m);
  float den = xe;
#pragma unroll
  for (int off = 32; off > 0; off >>= 1) den += __shfl_xor(den, off);
  float cp = xe * occ_sh[wave][lane];
#pragma unroll
  for (int off = 32; off > 0; off >>= 1) cp += __shfl_xor(cp, off);
  float ctx = cp / den;
#pragma unroll
  for (int j = 0; j < 16; j++) {
    int a = lane + j * 64;
    pool[(size_t)p * 1024 + a] = f2bf(fmaf(ctx, w0[a], P1[(size_t)p * 1024 + a]));
  }
}

// ---------------------------------------------------------------- batchnorm+relu (validated)
__global__ void k_norm(const ushort_t* __restrict__ y_mf,
                       const float* __restrict__ stats,
                       const float* __restrict__ gamma, const float* __restrict__ beta,
                       const ushort_t* __restrict__ hsrc, void* __restrict__ out) {
  int fl = block_flag(hsrc);
  int idx = (blockIdx.x * 256 + threadIdx.x) * 4;
  int col = idx & 1023;
  float vv[4];
#pragma unroll
  for (int j = 0; j < 4; j++) vv[j] = bf2f(y_mf[idx + j]);
  float4 s1 = *(const float4*)(stats + col);
  float4 s2 = *(const float4*)(stats + 1024 + col);
  float4 gm = *(const float4*)(gamma + col);
  float4 bt = *(const float4*)(beta + col);
  const float ib = 1.0f / 2048.0f;
  float m1[4] = {s1.x, s1.y, s1.z, s1.w};
  float m2[4] = {s2.x, s2.y, s2.z, s2.w};
  float gg[4] = {gm.x, gm.y, gm.z, gm.w};
  float bb[4] = {bt.x, bt.y, bt.z, bt.w};
  float o[4];
#pragma unroll
  for (int j = 0; j < 4; j++) {
    float mu = m1[j] * ib;
    float var = fmaf(-mu, mu, m2[j] * ib);
    o[j] = fmaxf(fmaf(gg[j] * (vv[j] - mu), rsqrtf(var + 1e-5f), bb[j]), 0.0f);
  }
  if (fl) {
    ushort4 ov = make_ushort4(f2bf(o[0]), f2bf(o[1]), f2bf(o[2]), f2bf(o[3]));
    *(ushort4*)((ushort_t*)out + idx) = ov;
  } else {
    *(float4*)((float*)out + idx) = make_float4(o[0], o[1], o[2], o[3]);
  }
}

// ---------------------------------------------------------------- launch
extern "C" void kernel_launch(void* const* d_in, const int* in_sizes, int n_in,
                              void* d_out, int out_size, void* d_ws, size_t ws_size,
                              hipStream_t stream) {
  float* ws = (float*)d_ws;
  float* conv   = ws;
  float* c_Wenc = conv + 0;
  float* c_benc = conv + 1024;
  float* c_bdec = conv + 2048;
  float* c_wful = conv + 3072;
  float* c_bout = conv + 4096;
  float* c_bmlp = conv + 5120;
  float* c_gam  = conv + 6144;
  float* c_bet  = conv + 7168;
  float* c_w0   = conv + 8192;
  float* occ    = ws + 9216;
  float* stats  = ws + 140288;
  float* P1     = ws + 142336;
  ushort_t* u0    = (ushort_t*)(ws + 2239488);
  ushort_t* hbf   = u0;
  ushort_t* WdecT = u0 + 131072;
  ushort_t* WoutT = u0 + 196608;
  ushort_t* WmlpT = u0 + 294912;
  ushort_t* Xcat0 = u0 + 1343488;
  ushort_t* y_mf  = u0 + 1540096;
  ushort_t* hd_bf   = (ushort_t*)d_out;   // validated d_out-as-scratch
  ushort_t* pool_mf = (ushort_t*)d_out;

  PrepPtrs ptrs;
  ptrs.p[0] = d_in[0];   // h (flag, h2b, Xcat0)
  ptrs.p[1] = d_in[6];   // W_dec (tp)
  ptrs.p[2] = d_in[10];  // W_out (tp rows 1..68)
  ptrs.p[3] = d_in[12];  // W_mlp (tp)
  ptrs.p[4] = d_in[1];   // end_pos (Xcat0, occupancy)
  ptrs.p[5] = d_in[2];   // rel_pos (Xcat0)
  ptrs.p[6] = d_in[3];   // scene (occupancy)
  ptrs.p[7]  = d_in[4];  // W_enc  (conv seg0)
  ptrs.p[8]  = d_in[5];  // b_enc  (seg1)
  ptrs.p[9]  = d_in[7];  // b_dec  (seg2)
  ptrs.p[10] = d_in[8];  // w_full (seg3)
  ptrs.p[11] = d_in[11]; // b_out  (seg4)
  ptrs.p[12] = d_in[13]; // b_mlp  (seg5)
  ptrs.p[13] = d_in[14]; // gamma  (seg6)
  ptrs.p[14] = d_in[15]; // beta   (seg7)
  ptrs.p[15] = d_in[10]; // w0 = W_out row 0 (seg8)

  k_prep<<<3562, 256, 0, stream>>>(ptrs, conv, hbf, WdecT, WoutT, WmlpT,
                                   Xcat0, occ, stats);

  k_gemm2<<<dim3(32, 8, 2), 256, 0, stream>>>(hbf, WdecT, c_benc, c_bdec, hd_bf,
                                              Xcat0, WoutT, c_bout, P1);

  k_ectx<<<512, 256, 0, stream>>>(occ, c_Wenc, c_wful, c_w0, P1, hd_bf, pool_mf);

  k_ygemm<<<dim3(32, 16), 256, 0, stream>>>(pool_mf, WmlpT, c_bmlp, y_mf, stats);

  k_norm<<<2048, 256, 0, stream>>>(y_mf, stats, c_gam, c_bet,
                                   (const ushort_t*)d_in[0], d_out);
}